// Round 5
// baseline (265.318 us; speedup 1.0000x reference)
//
#include <hip/hip_runtime.h>

#define NNODES 100000
#define DIM 64
#define NSUB 4   // sublists per node (MLP factor for the list walk)

// One pass over edges: push e onto sublist (e&3) of dst, count out-degree of src.
__global__ void build_kernel(const int* __restrict__ src, const int* __restrict__ dst,
                             int* __restrict__ head, int* __restrict__ outdeg,
                             int* __restrict__ nxt, int E) {
    int e = blockIdx.x * blockDim.x + threadIdx.x;
    if (e < E) {
        int d = dst[e];
        int s = src[e];
        nxt[e] = atomicExch(&head[(e & (NSUB - 1)) * NNODES + d], e);
        atomicAdd(&outdeg[s], 1);
    }
}

// One wave per destination node; lane = feature dim (DIM == 64 == wavefront).
// Walk NSUB independent edge lists concurrently -> NSUB outstanding chases.
__global__ void aggregate_kernel(const float* __restrict__ emb,
                                 const int* __restrict__ head,
                                 const int* __restrict__ nxt,
                                 const int* __restrict__ src,
                                 const int* __restrict__ outdeg,
                                 float* __restrict__ out, int n) {
    int wid = threadIdx.x >> 6;
    int lane = threadIdx.x & 63;
    int node = blockIdx.x * (blockDim.x >> 6) + wid;
    if (node >= n) return;

    int e0 = head[0 * NNODES + node];
    int e1 = head[1 * NNODES + node];
    int e2 = head[2 * NNODES + node];
    int e3 = head[3 * NNODES + node];

    float acc = 0.0f;
    int cnt = 0;
    // (e0 & e1 & e2 & e3) == -1 iff all four are -1 (list end sentinel).
    while ((e0 & e1 & e2 & e3) != -1) {
        if (e0 >= 0) {
            int s = src[e0]; int en = nxt[e0];
            float w = rsqrtf(fmaxf((float)outdeg[s], 1.0f));
            acc = fmaf(emb[(size_t)s * DIM + lane], w, acc);
            cnt++; e0 = en;
        }
        if (e1 >= 0) {
            int s = src[e1]; int en = nxt[e1];
            float w = rsqrtf(fmaxf((float)outdeg[s], 1.0f));
            acc = fmaf(emb[(size_t)s * DIM + lane], w, acc);
            cnt++; e1 = en;
        }
        if (e2 >= 0) {
            int s = src[e2]; int en = nxt[e2];
            float w = rsqrtf(fmaxf((float)outdeg[s], 1.0f));
            acc = fmaf(emb[(size_t)s * DIM + lane], w, acc);
            cnt++; e2 = en;
        }
        if (e3 >= 0) {
            int s = src[e3]; int en = nxt[e3];
            float w = rsqrtf(fmaxf((float)outdeg[s], 1.0f));
            acc = fmaf(emb[(size_t)s * DIM + lane], w, acc);
            cnt++; e3 = en;
        }
    }
    float dn = rsqrtf(fmaxf((float)cnt, 1.0f));
    out[(size_t)node * DIM + lane] = acc * dn;
}

extern "C" void kernel_launch(void* const* d_in, const int* in_sizes, int n_in,
                              void* d_out, int out_size, void* d_ws, size_t ws_size,
                              hipStream_t stream) {
    const float* emb = (const float*)d_in[0];
    const int* src = (const int*)d_in[1];
    const int* dst = (const int*)d_in[2];
    int E = in_sizes[1];

    int* head = (int*)d_ws;                    // [NSUB * N]
    int* outdeg = head + NSUB * NNODES;        // [N]
    int* nxt = outdeg + NNODES;                // [E]
    float* out = (float*)d_out;

    hipMemsetAsync(head, 0xFF, NSUB * NNODES * sizeof(int), stream);  // head = -1
    hipMemsetAsync(outdeg, 0, NNODES * sizeof(int), stream);

    build_kernel<<<(E + 255) / 256, 256, 0, stream>>>(src, dst, head, outdeg, nxt, E);

    int waves_per_block = 4;  // 256 threads
    int blocks = (NNODES + waves_per_block - 1) / waves_per_block;
    aggregate_kernel<<<blocks, 256, 0, stream>>>(emb, head, nxt, src, outdeg, out, NNODES);
}

// Round 6
// 199.717 us; speedup vs baseline: 1.3285x; 1.3285x over previous
//
#include <hip/hip_runtime.h>
#include <hip/hip_fp16.h>

#define NNODES 100000
#define DIM 64
#define K_SLOTS 32   // 32 ints = 128B per node, 2 cache lines, covers Poisson(12.5) to ~6 sigma
#define NSUB 4

// ---------- fast path ----------

__global__ void convert_kernel(const float* __restrict__ emb, __half* __restrict__ embh, int total8) {
    int i = blockIdx.x * blockDim.x + threadIdx.x;
    if (i < total8) {
        int base = i * 8;
        float4 a = *(const float4*)(emb + base);
        float4 b = *(const float4*)(emb + base + 4);
        __half2* o = (__half2*)(embh + base);
        o[0] = __floats2half2_rn(a.x, a.y);
        o[1] = __floats2half2_rn(a.z, a.w);
        o[2] = __floats2half2_rn(b.x, b.y);
        o[3] = __floats2half2_rn(b.z, b.w);
    }
}

// One pass: out-degree count + bucket fill (overflow -> linked list, ~never taken).
__global__ void build_slots_kernel(const int* __restrict__ src, const int* __restrict__ dst,
                                   int* __restrict__ cnt, int* __restrict__ outdeg,
                                   int* __restrict__ ohead, int* __restrict__ nxt,
                                   int* __restrict__ slots, int E) {
    int e = blockIdx.x * blockDim.x + threadIdx.x;
    if (e < E) {
        int d = dst[e];
        int s = src[e];
        atomicAdd(&outdeg[s], 1);
        int pos = atomicAdd(&cnt[d], 1);
        if (pos < K_SLOTS) slots[d * K_SLOTS + pos] = s;
        else nxt[e] = atomicExch(&ohead[d], e);
    }
}

__global__ void norm_kernel(const int* __restrict__ outdeg, float* __restrict__ src_norm, int n4) {
    int i = blockIdx.x * blockDim.x + threadIdx.x;
    if (i < n4) {
        int base = i * 4;
        int4 v = *(const int4*)(outdeg + base);
        float4 sn;
        sn.x = rsqrtf(fmaxf((float)v.x, 1.0f));
        sn.y = rsqrtf(fmaxf((float)v.y, 1.0f));
        sn.z = rsqrtf(fmaxf((float)v.z, 1.0f));
        sn.w = rsqrtf(fmaxf((float)v.w, 1.0f));
        *(float4*)(src_norm + base) = sn;
    }
}

// One wave per dst node; lane = feature. Contiguous slot reads, 4 gathers in flight.
__global__ void aggregate_kernel(const __half* __restrict__ embh,
                                 const int* __restrict__ cnt,
                                 const int* __restrict__ slots,
                                 const int* __restrict__ ohead,
                                 const int* __restrict__ nxt,
                                 const int* __restrict__ srcArr,
                                 const float* __restrict__ src_norm,
                                 float* __restrict__ out, int n) {
    int wid = threadIdx.x >> 6;
    int lane = threadIdx.x & 63;
    int node = blockIdx.x * (blockDim.x >> 6) + wid;
    if (node >= n) return;
    int deg = cnt[node];
    int m = min(deg, K_SLOTS);
    const int* sl = slots + (size_t)node * K_SLOTS;
    float acc = 0.0f;
    int j = 0;
    for (; j + 4 <= m; j += 4) {
        int4 ss = *(const int4*)(sl + j);
        float w0 = src_norm[ss.x];
        float w1 = src_norm[ss.y];
        float w2 = src_norm[ss.z];
        float w3 = src_norm[ss.w];
        float e0 = __half2float(embh[(size_t)ss.x * DIM + lane]);
        float e1 = __half2float(embh[(size_t)ss.y * DIM + lane]);
        float e2 = __half2float(embh[(size_t)ss.z * DIM + lane]);
        float e3 = __half2float(embh[(size_t)ss.w * DIM + lane]);
        acc = fmaf(e0, w0, acc);
        acc = fmaf(e1, w1, acc);
        acc = fmaf(e2, w2, acc);
        acc = fmaf(e3, w3, acc);
    }
    for (; j < m; j++) {
        int s = sl[j];
        acc = fmaf(__half2float(embh[(size_t)s * DIM + lane]), src_norm[s], acc);
    }
    if (deg > K_SLOTS) {  // rare overflow path
        int e = ohead[node];
        while (e >= 0) {
            int s = srcArr[e];
            acc = fmaf(__half2float(embh[(size_t)s * DIM + lane]), src_norm[s], acc);
            e = nxt[e];
        }
    }
    float dn = rsqrtf(fmaxf((float)deg, 1.0f));
    out[(size_t)node * DIM + lane] = acc * dn;
}

// ---------- fallback path (round-5, small ws) ----------

__global__ void build_ll_kernel(const int* __restrict__ src, const int* __restrict__ dst,
                                int* __restrict__ head, int* __restrict__ outdeg,
                                int* __restrict__ nxt, int E) {
    int e = blockIdx.x * blockDim.x + threadIdx.x;
    if (e < E) {
        int d = dst[e];
        int s = src[e];
        nxt[e] = atomicExch(&head[(e & (NSUB - 1)) * NNODES + d], e);
        atomicAdd(&outdeg[s], 1);
    }
}

__global__ void aggregate_ll_kernel(const float* __restrict__ emb,
                                    const int* __restrict__ head,
                                    const int* __restrict__ nxt,
                                    const int* __restrict__ src,
                                    const int* __restrict__ outdeg,
                                    float* __restrict__ out, int n) {
    int wid = threadIdx.x >> 6;
    int lane = threadIdx.x & 63;
    int node = blockIdx.x * (blockDim.x >> 6) + wid;
    if (node >= n) return;
    int e0 = head[0 * NNODES + node];
    int e1 = head[1 * NNODES + node];
    int e2 = head[2 * NNODES + node];
    int e3 = head[3 * NNODES + node];
    float acc = 0.0f;
    int cnt = 0;
    while ((e0 & e1 & e2 & e3) != -1) {
        if (e0 >= 0) { int s = src[e0]; int en = nxt[e0];
            acc = fmaf(emb[(size_t)s * DIM + lane], rsqrtf(fmaxf((float)outdeg[s], 1.0f)), acc); cnt++; e0 = en; }
        if (e1 >= 0) { int s = src[e1]; int en = nxt[e1];
            acc = fmaf(emb[(size_t)s * DIM + lane], rsqrtf(fmaxf((float)outdeg[s], 1.0f)), acc); cnt++; e1 = en; }
        if (e2 >= 0) { int s = src[e2]; int en = nxt[e2];
            acc = fmaf(emb[(size_t)s * DIM + lane], rsqrtf(fmaxf((float)outdeg[s], 1.0f)), acc); cnt++; e2 = en; }
        if (e3 >= 0) { int s = src[e3]; int en = nxt[e3];
            acc = fmaf(emb[(size_t)s * DIM + lane], rsqrtf(fmaxf((float)outdeg[s], 1.0f)), acc); cnt++; e3 = en; }
    }
    float dn = rsqrtf(fmaxf((float)cnt, 1.0f));
    out[(size_t)node * DIM + lane] = acc * dn;
}

extern "C" void kernel_launch(void* const* d_in, const int* in_sizes, int n_in,
                              void* d_out, int out_size, void* d_ws, size_t ws_size,
                              hipStream_t stream) {
    const float* emb = (const float*)d_in[0];
    const int* src = (const int*)d_in[1];
    const int* dst = (const int*)d_in[2];
    int E = in_sizes[1];
    float* out = (float*)d_out;

    size_t needed = ((size_t)3 * NNODES + (size_t)E + (size_t)NNODES * K_SLOTS + NNODES) * 4
                  + (size_t)NNODES * DIM * 2;

    if (ws_size >= needed) {
        int* cnt = (int*)d_ws;                                   // [N]
        int* outdeg = cnt + NNODES;                              // [N]
        int* ohead = outdeg + NNODES;                            // [N]
        int* nxt = ohead + NNODES;                               // [E]
        int* slots = nxt + E;                                    // [N*K]
        float* src_norm = (float*)(slots + (size_t)NNODES * K_SLOTS);  // [N]
        __half* embh = (__half*)(src_norm + NNODES);             // [N*DIM]

        hipMemsetAsync(cnt, 0, 2 * NNODES * sizeof(int), stream);
        hipMemsetAsync(ohead, 0xFF, NNODES * sizeof(int), stream);

        int total8 = NNODES * DIM / 8;
        convert_kernel<<<(total8 + 255) / 256, 256, 0, stream>>>(emb, embh, total8);
        build_slots_kernel<<<(E + 255) / 256, 256, 0, stream>>>(src, dst, cnt, outdeg, ohead, nxt, slots, E);
        norm_kernel<<<(NNODES / 4 + 255) / 256, 256, 0, stream>>>(outdeg, src_norm, NNODES / 4);

        aggregate_kernel<<<(NNODES + 3) / 4, 256, 0, stream>>>(embh, cnt, slots, ohead, nxt, src,
                                                               src_norm, out, NNODES);
    } else {
        int* head = (int*)d_ws;                    // [NSUB*N]
        int* outdeg = head + NSUB * NNODES;        // [N]
        int* nxt = outdeg + NNODES;                // [E]
        hipMemsetAsync(head, 0xFF, NSUB * NNODES * sizeof(int), stream);
        hipMemsetAsync(outdeg, 0, NNODES * sizeof(int), stream);
        build_ll_kernel<<<(E + 255) / 256, 256, 0, stream>>>(src, dst, head, outdeg, nxt, E);
        aggregate_ll_kernel<<<(NNODES + 3) / 4, 256, 0, stream>>>(emb, head, nxt, src, outdeg, out, NNODES);
    }
}